// Round 1
// baseline (376.027 us; speedup 1.0000x reference)
//
#include <hip/hip_runtime.h>
#include <hip/hip_bf16.h>

#define BATCH   16
#define NELEM   131072
#define PRE_NMS 2048
#define POST_NMS 512
#define NBKT    8192      // 13-bit score-prefix buckets
#define CAP     4096      // candidate capacity per image
#define SORT_N  4096

// ws layout (bytes):
//   [0,        524288)  hist  : B * NBKT * u32
//   [524288,   524352)  cnt   : B * u32
//   [524416,   524480)  cutb  : B * u32
//   [524544,  1048832)  cand  : B * CAP * u64
#define OFF_CNT  524288
#define OFF_CUT  524416
#define OFF_CAND 524544

__device__ __forceinline__ unsigned int okey_f32(float f) {
  unsigned int u = __float_as_uint(f);
  return (u & 0x80000000u) ? ~u : (u | 0x80000000u);  // ascending uint == ascending float
}

__global__ void hist_kernel(const float* __restrict__ obj, unsigned int* __restrict__ hist) {
  int b = blockIdx.x >> 5, seg = blockIdx.x & 31;
  __shared__ unsigned int lh[NBKT];
  for (int i = threadIdx.x; i < NBKT; i += 256) lh[i] = 0u;
  __syncthreads();
  const float* p = obj + (size_t)b * NELEM + (size_t)seg * 4096;
#pragma unroll
  for (int k = 0; k < 16; ++k) {
    float v = p[threadIdx.x + k * 256];
    atomicAdd(&lh[okey_f32(v) >> 19], 1u);
  }
  __syncthreads();
  unsigned int* gh = hist + (size_t)b * NBKT;
  for (int i = threadIdx.x; i < NBKT; i += 256) {
    unsigned int c = lh[i];
    if (c) atomicAdd(&gh[i], c);
  }
}

__global__ void cut_kernel(const unsigned int* __restrict__ hist, unsigned int* __restrict__ cutb) {
  int b = blockIdx.x, t = threadIdx.x;
  const unsigned int* h = hist + (size_t)b * NBKT;
  unsigned int loc[32];
  unsigned int s = 0;
#pragma unroll
  for (int k = 0; k < 32; ++k) { loc[k] = h[t * 32 + k]; s += loc[k]; }
  __shared__ unsigned int sa[256], sb[256];
  sa[t] = s;
  __syncthreads();
  unsigned int* cur = sa; unsigned int* nxt = sb;
  for (int d = 1; d < 256; d <<= 1) {           // inclusive suffix scan
    nxt[t] = cur[t] + ((t + d < 256) ? cur[t + d] : 0u);
    __syncthreads();
    unsigned int* tmp = cur; cur = nxt; nxt = tmp;
  }
  unsigned int above = cur[t] - s;              // sum of buckets owned by threads > t
  unsigned int run = above;
#pragma unroll
  for (int k = 31; k >= 0; --k) {               // sweep own buckets high -> low
    unsigned int prev = run; run += loc[k];
    if (prev < PRE_NMS && run >= PRE_NMS) cutb[b] = (unsigned int)(t * 32 + k);
  }
}

__global__ void collect_kernel(const float* __restrict__ obj, const unsigned int* __restrict__ cutb,
                               unsigned int* __restrict__ cnt, unsigned long long* __restrict__ cand) {
  int b = blockIdx.x >> 5, seg = blockIdx.x & 31;
  __shared__ unsigned long long buf[4096];
  __shared__ unsigned int lcnt, gbase;
  if (threadIdx.x == 0) lcnt = 0u;
  __syncthreads();
  unsigned int c = cutb[b];
  const float* p = obj + (size_t)b * NELEM + (size_t)seg * 4096;
#pragma unroll
  for (int k = 0; k < 16; ++k) {
    int li = threadIdx.x + k * 256;
    unsigned int ok = okey_f32(p[li]);
    if ((ok >> 19) >= c) {
      unsigned int pos = atomicAdd(&lcnt, 1u);
      buf[pos] = ((unsigned long long)(~ok) << 32) | (unsigned int)(seg * 4096 + li);
    }
  }
  __syncthreads();
  if (threadIdx.x == 0) gbase = atomicAdd(&cnt[b], lcnt);
  __syncthreads();
  unsigned long long* cb = cand + (size_t)b * CAP;
  unsigned int n = lcnt, g = gbase;
  for (unsigned int i = threadIdx.x; i < n; i += 256) {
    unsigned int d = g + i;
    if (d < CAP) cb[d] = buf[i];
  }
}

__device__ __forceinline__ bool iou_gt_half(float2 a, float aa, float2 b, float ab) {
  // exact IEEE ops, no contraction: matches jnp inter/union/iou > 0.5
  float inter = fmaxf(__fsub_rn(fminf(a.y, b.y), fmaxf(a.x, b.x)), 0.0f);
  float uni = __fsub_rn(__fadd_rn(aa, ab), inter);
  float q = __fdiv_rn(inter, fmaxf(uni, 1e-6f));
  return q > 0.5f;
}

__global__ __launch_bounds__(512) void finalize_kernel(
    const float* __restrict__ delta, const float* __restrict__ anchor,
    const int* __restrict__ imgp,
    const unsigned int* __restrict__ cnt, const unsigned long long* __restrict__ cand,
    float* __restrict__ out) {
  __shared__ unsigned long long skey[SORT_N];   // 32 KB
  __shared__ float2 box[PRE_NMS];               // 16 KB
  __shared__ unsigned short Lpos[PRE_NMS];      // 4 KB  (kept-candidate positions)
  __shared__ unsigned int keepw[PRE_NMS / 32];  // 64 words of keep bits
  __shared__ unsigned long long ballots[8];
  __shared__ unsigned int wpre[65];
  __shared__ unsigned int LcntS;

  int b = blockIdx.x, t = threadIdx.x;
  int wave = t >> 6, lane = t & 63;

  unsigned int C = cnt[b]; if (C > SORT_N) C = SORT_N;
  const unsigned long long* cb = cand + (size_t)b * CAP;
  for (int i = t; i < SORT_N; i += 512)
    skey[i] = (i < (int)C) ? cb[i] : 0xFFFFFFFFFFFFFFFFULL;
  __syncthreads();

  // bitonic sort ascending: key = (~okey<<32)|idx  => score desc, index asc
  for (int k = 2; k <= SORT_N; k <<= 1) {
    for (int j = k >> 1; j > 0; j >>= 1) {
      for (int i = t; i < SORT_N; i += 512) {
        int ixj = i ^ j;
        if (ixj > i) {
          unsigned long long a = skey[i], c2 = skey[ixj];
          bool up = (i & k) == 0;
          if (up ? (a > c2) : (a < c2)) { skey[i] = c2; skey[ixj] = a; }
        }
      }
      __syncthreads();
    }
  }

  // decode + clip top-2048
  int iv = imgp[0];
  float img = (iv > 0 && iv < 1000000) ? (float)iv : __int_as_float(iv);
  const float2* d2 = (const float2*)delta;
  const float2* a2 = (const float2*)anchor;
  for (int p = t; p < PRE_NMS; p += 512) {
    unsigned int idx = (unsigned int)skey[p];
    float2 dd = d2[(size_t)b * NELEM + idx];
    float2 aa = a2[(size_t)b * NELEM + idx];
    float aw = __fsub_rn(aa.y, aa.x);
    float ac = __fadd_rn(aa.x, __fmul_rn(0.5f, aw));
    float dw = fminf(dd.y, 4.0f);
    float pc = __fadd_rn(__fmul_rn(dd.x, aw), ac);
    float pw = __fmul_rn(expf(dw), aw);
    float hx = __fmul_rn(0.5f, pw);
    float x1 = __fsub_rn(pc, hx);
    float x2 = __fadd_rn(pc, hx);
    x1 = fminf(fmaxf(x1, 0.0f), img);
    x2 = fminf(fmaxf(x2, 0.0f), img);
    box[p] = make_float2(x1, x2);
  }
  if (t == 0) LcntS = 0u;
  __syncthreads();

  // greedy NMS, 32 chunks of 64 (exactly equivalent to the reference scan)
  for (int ch = 0; ch < 32; ++ch) {
    int base = ch * 64;
    float2 bj = box[base + lane];
    float aj = __fsub_rn(bj.y, bj.x);
    bool sup = false;
    unsigned int Ln = LcntS;
    for (unsigned int l = wave; l < Ln; l += 8) {   // check vs already-kept list, 8-way wave parallel
      float2 bi = box[Lpos[l]];
      float ai = __fsub_rn(bi.y, bi.x);
      sup = sup || iou_gt_half(bj, aj, bi, ai);
    }
    unsigned long long bal = __ballot(sup);
    if (lane == 0) ballots[wave] = bal;
    __syncthreads();
    if (wave == 0) {
      unsigned long long s = ballots[0];
#pragma unroll
      for (int w2 = 1; w2 < 8; ++w2) s |= ballots[w2];
      for (int i = 0; i < 64; ++i) {                // serial in-chunk scan (uniform branch)
        if ((s >> i) & 1ULL) continue;
        float2 bi = box[base + i];
        float ai = __fsub_rn(bi.y, bi.x);
        unsigned long long bb2 = __ballot(iou_gt_half(bj, aj, bi, ai));
        bb2 &= ~(1ULL << i);                        // diag zeroed as in reference
        s |= bb2;
      }
      unsigned long long keepm = ~s;
      unsigned int Lc = LcntS;
      if (lane == 0) {
        keepw[ch * 2]     = (unsigned int)keepm;
        keepw[ch * 2 + 1] = (unsigned int)(keepm >> 32);
      }
      unsigned int rank = __popcll(keepm & ((1ULL << lane) - 1ULL));
      if ((keepm >> lane) & 1ULL) Lpos[Lc + rank] = (unsigned short)(base + lane);
      if (lane == 0) LcntS = Lc + (unsigned int)__popcll(keepm);
    }
    __syncthreads();
  }

  // stable partition: kept positions first (ascending), then unkept (ascending)
  if (wave == 0) {
    unsigned int wv = keepw[lane];
    unsigned int pc = __popc(wv);
    unsigned int inc = pc;
    for (int d = 1; d < 64; d <<= 1) {
      unsigned int v = __shfl_up(inc, d);
      if (lane >= d) inc += v;
    }
    wpre[lane] = inc - pc;
    if (lane == 63) wpre[64] = inc;
  }
  __syncthreads();
  unsigned int K = wpre[64];
  size_t selOff = (size_t)BATCH * POST_NMS * 2;
  size_t valOff = selOff + (size_t)BATCH * POST_NMS;
  for (int p = t; p < PRE_NMS; p += 512) {
    unsigned int w = p >> 5, bit = p & 31;
    unsigned int wv = keepw[w];
    bool kp = (wv >> bit) & 1u;
    unsigned int kpref = wpre[w] + __popc(wv & ((1u << bit) - 1u));
    unsigned int r = kp ? kpref : (K + ((unsigned int)p - kpref));
    if (r < POST_NMS) {
      float2 bx = kp ? box[p] : make_float2(0.0f, 0.0f);
      size_t ob = (size_t)b * POST_NMS + r;
      out[ob * 2 + 0] = bx.x;
      out[ob * 2 + 1] = bx.y;
      out[selOff + ob] = (float)p;          // sel index, exact in f32
      out[valOff + ob] = kp ? 1.0f : 0.0f;  // valid flag
    }
  }
}

extern "C" void kernel_launch(void* const* d_in, const int* in_sizes, int n_in,
                              void* d_out, int out_size, void* d_ws, size_t ws_size,
                              hipStream_t stream) {
  const float* obj    = (const float*)d_in[0];
  const float* delta  = (const float*)d_in[1];
  const float* anchor = (const float*)d_in[2];
  const int*   imgp   = (const int*)d_in[3];
  float* out = (float*)d_out;

  unsigned char* w = (unsigned char*)d_ws;
  unsigned int* hist       = (unsigned int*)(w);
  unsigned int* cnt        = (unsigned int*)(w + OFF_CNT);
  unsigned int* cutb       = (unsigned int*)(w + OFF_CUT);
  unsigned long long* cand = (unsigned long long*)(w + OFF_CAND);

  // zero hist + cnt (ws is NOT re-poisoned between replays; we must re-init)
  hipMemsetAsync(w, 0, OFF_CUT, stream);

  hist_kernel<<<dim3(512), dim3(256), 0, stream>>>(obj, hist);
  cut_kernel<<<dim3(BATCH), dim3(256), 0, stream>>>(hist, cutb);
  collect_kernel<<<dim3(512), dim3(256), 0, stream>>>(obj, cutb, cnt, cand);
  finalize_kernel<<<dim3(BATCH), dim3(512), 0, stream>>>(delta, anchor, imgp, cnt, cand, out);
}

// Round 2
// 245.972 us; speedup vs baseline: 1.5287x; 1.5287x over previous
//
#include <hip/hip_runtime.h>
#include <hip/hip_bf16.h>

#define BATCH   16
#define NELEM   131072
#define PRE_NMS 2048
#define POST_NMS 512
#define NBKT    8192      // 13-bit score-prefix buckets
#define CAP     4096      // candidate capacity per image
#define SORT_N  4096
#define NTHR    1024
#define NCH     32        // 32 chunks of 64 candidates

// ws layout (bytes):
#define OFF_CNT  524288
#define OFF_CUT  524416
#define OFF_CAND 524544

__device__ __forceinline__ unsigned int okey_f32(float f) {
  unsigned int u = __float_as_uint(f);
  return (u & 0x80000000u) ? ~u : (u | 0x80000000u);  // ascending uint == ascending float
}

__global__ void hist_kernel(const float* __restrict__ obj, unsigned int* __restrict__ hist) {
  int b = blockIdx.x >> 5, seg = blockIdx.x & 31;
  __shared__ unsigned int lh[NBKT];
  for (int i = threadIdx.x; i < NBKT; i += 256) lh[i] = 0u;
  __syncthreads();
  const float* p = obj + (size_t)b * NELEM + (size_t)seg * 4096;
#pragma unroll
  for (int k = 0; k < 16; ++k) {
    float v = p[threadIdx.x + k * 256];
    atomicAdd(&lh[okey_f32(v) >> 19], 1u);
  }
  __syncthreads();
  unsigned int* gh = hist + (size_t)b * NBKT;
  for (int i = threadIdx.x; i < NBKT; i += 256) {
    unsigned int c = lh[i];
    if (c) atomicAdd(&gh[i], c);
  }
}

__global__ void cut_kernel(const unsigned int* __restrict__ hist, unsigned int* __restrict__ cutb) {
  int b = blockIdx.x, t = threadIdx.x;
  const unsigned int* h = hist + (size_t)b * NBKT;
  unsigned int loc[32];
  unsigned int s = 0;
#pragma unroll
  for (int k = 0; k < 32; ++k) { loc[k] = h[t * 32 + k]; s += loc[k]; }
  __shared__ unsigned int sa[256], sb[256];
  sa[t] = s;
  __syncthreads();
  unsigned int* cur = sa; unsigned int* nxt = sb;
  for (int d = 1; d < 256; d <<= 1) {           // inclusive suffix scan
    nxt[t] = cur[t] + ((t + d < 256) ? cur[t + d] : 0u);
    __syncthreads();
    unsigned int* tmp = cur; cur = nxt; nxt = tmp;
  }
  unsigned int above = cur[t] - s;              // sum of buckets owned by threads > t
  unsigned int run = above;
#pragma unroll
  for (int k = 31; k >= 0; --k) {               // sweep own buckets high -> low
    unsigned int prev = run; run += loc[k];
    if (prev < PRE_NMS && run >= PRE_NMS) cutb[b] = (unsigned int)(t * 32 + k);
  }
}

__global__ void collect_kernel(const float* __restrict__ obj, const unsigned int* __restrict__ cutb,
                               unsigned int* __restrict__ cnt, unsigned long long* __restrict__ cand) {
  int b = blockIdx.x >> 5, seg = blockIdx.x & 31;
  __shared__ unsigned long long buf[4096];
  __shared__ unsigned int lcnt, gbase;
  if (threadIdx.x == 0) lcnt = 0u;
  __syncthreads();
  unsigned int c = cutb[b];
  const float* p = obj + (size_t)b * NELEM + (size_t)seg * 4096;
#pragma unroll
  for (int k = 0; k < 16; ++k) {
    int li = threadIdx.x + k * 256;
    unsigned int ok = okey_f32(p[li]);
    if ((ok >> 19) >= c) {
      unsigned int pos = atomicAdd(&lcnt, 1u);
      buf[pos] = ((unsigned long long)(~ok) << 32) | (unsigned int)(seg * 4096 + li);
    }
  }
  __syncthreads();
  if (threadIdx.x == 0) gbase = atomicAdd(&cnt[b], lcnt);
  __syncthreads();
  unsigned long long* cb = cand + (size_t)b * CAP;
  unsigned int n = lcnt, g = gbase;
  for (unsigned int i = threadIdx.x; i < n; i += 256) {
    unsigned int d = g + i;
    if (d < CAP) cb[d] = buf[i];
  }
}

__device__ __forceinline__ bool iou_gt_half(float2 a, float aa, float2 b, float ab) {
  // exact IEEE ops, no contraction: matches jnp inter/union/iou > 0.5
  float inter = fmaxf(__fsub_rn(fminf(a.y, b.y), fmaxf(a.x, b.x)), 0.0f);
  float uni = __fsub_rn(__fadd_rn(aa, ab), inter);
  float q = __fdiv_rn(inter, fmaxf(uni, 1e-6f));
  return q > 0.5f;
}

__device__ __forceinline__ float2 decode_one(const float2* __restrict__ d2,
                                             const float2* __restrict__ a2,
                                             size_t base, unsigned int idx, float img) {
  float2 dd = d2[base + idx];
  float2 aa = a2[base + idx];
  float aw = __fsub_rn(aa.y, aa.x);
  float ac = __fadd_rn(aa.x, __fmul_rn(0.5f, aw));
  float dw = fminf(dd.y, 4.0f);
  float pc = __fadd_rn(__fmul_rn(dd.x, aw), ac);
  float pw = __fmul_rn(expf(dw), aw);
  float hx = __fmul_rn(0.5f, pw);
  float x1 = fminf(fmaxf(__fsub_rn(pc, hx), 0.0f), img);
  float x2 = fminf(fmaxf(__fadd_rn(pc, hx), 0.0f), img);
  return make_float2(x1, x2);
}

__global__ __launch_bounds__(NTHR) void finalize_kernel(
    const float* __restrict__ delta, const float* __restrict__ anchor,
    const int* __restrict__ imgp,
    const unsigned int* __restrict__ cnt, const unsigned long long* __restrict__ cand,
    float* __restrict__ out) {
  __shared__ union UBuf {
    unsigned long long skey[SORT_N];       // 32 KB (sort phase)
    unsigned long long rowm[NCH][64];      // 16 KB (NMS phase, reuses same space)
  } u;
  __shared__ float2 box[PRE_NMS];          // 16 KB
  __shared__ unsigned short Lpos[PRE_NMS]; // 4 KB  (kept-candidate positions)
  __shared__ unsigned int keepw[NCH * 2];  // 64 words of keep bits
  __shared__ unsigned int wpre[65];
  __shared__ unsigned int LcntS;

  int b = blockIdx.x, t = threadIdx.x;
  int wv = t >> 6, lane = t & 63;

  // ---- load candidates ----
  unsigned int C = cnt[b]; if (C > SORT_N) C = SORT_N;
  const unsigned long long* cb = cand + (size_t)b * CAP;
  for (int i = t; i < SORT_N; i += NTHR)
    u.skey[i] = (i < (int)C) ? cb[i] : 0xFFFFFFFFFFFFFFFFULL;
  __syncthreads();

  // ---- bitonic sort ascending: key = (~okey<<32)|idx => score desc, index asc ----
  for (int k = 2; k <= SORT_N; k <<= 1) {
    for (int j = k >> 1; j > 0; j >>= 1) {
      for (int i = t; i < SORT_N; i += NTHR) {
        int ixj = i ^ j;
        if (ixj > i) {
          unsigned long long a = u.skey[i], c2 = u.skey[ixj];
          bool up = (i & k) == 0;
          if (up ? (a > c2) : (a < c2)) { u.skey[i] = c2; u.skey[ixj] = a; }
        }
      }
      __syncthreads();
    }
  }

  // ---- decode + clip top-2048; each thread owns candidates t and t+1024 ----
  int iv = imgp[0];
  float img = (iv > 0 && iv < 1000000) ? (float)iv : __int_as_float(iv);
  const float2* d2 = (const float2*)delta;
  const float2* a2 = (const float2*)anchor;
  size_t base = (size_t)b * NELEM;

  float2 bx0 = decode_one(d2, a2, base, (unsigned int)u.skey[t], img);
  float2 bx1 = decode_one(d2, a2, base, (unsigned int)u.skey[t + NTHR], img);
  float ar0 = __fsub_rn(bx0.y, bx0.x);
  float ar1 = __fsub_rn(bx1.y, bx1.x);
  bool sup0 = false, sup1 = false;
  box[t] = bx0;
  box[t + NTHR] = bx1;
  if (t == 0) LcntS = 0u;
  __syncthreads();   // skey reads done; box[] complete

  // ---- precompute in-chunk 64x64 adjacency rowmasks (reuses skey memory) ----
  // thread (wv,lane) owns row `lane` of chunk wv (r=0) and chunk wv+16 (r=1)
  {
    unsigned long long m0 = 0ull, m1 = 0ull;
    int c0 = wv, c1 = wv + 16;
    for (int j = 0; j < 64; ++j) {
      float2 bb0 = box[c0 * 64 + j];
      float2 bb1 = box[c1 * 64 + j];
      float ab0 = __fsub_rn(bb0.y, bb0.x);
      float ab1 = __fsub_rn(bb1.y, bb1.x);
      unsigned long long s0 = (iou_gt_half(bx0, ar0, bb0, ab0) && (j != lane)) ? 1ull : 0ull;
      unsigned long long s1 = (iou_gt_half(bx1, ar1, bb1, ab1) && (j != lane)) ? 1ull : 0ull;
      m0 |= s0 << j;
      m1 |= s1 << j;
    }
    u.rowm[c0][lane] = m0;
    u.rowm[c1][lane] = m1;
  }
  __syncthreads();

  // ---- serial greedy NMS over 32 chunks ----
  // cross-chunk suppression is incremental: every thread updates its 2 owned
  // candidates against newly kept boxes; in-chunk handled by rowmask scalar scan.
  unsigned int updL = 0;
  for (int ch = 0; ch < NCH; ++ch) {
    unsigned int Lc = LcntS;
    for (unsigned int l = updL; l < Lc; ++l) {
      float2 bi = box[Lpos[l]];
      float ai = __fsub_rn(bi.y, bi.x);
      sup0 = sup0 || iou_gt_half(bx0, ar0, bi, ai);
      sup1 = sup1 || iou_gt_half(bx1, ar1, bi, ai);
    }
    updL = Lc;
    __syncthreads();   // (A) everyone done reading Lpos/LcntS old state
    if (wv == (ch & 15)) {
      bool mysup = (ch < 16) ? sup0 : sup1;
      unsigned long long s = __ballot(mysup);
      unsigned long long myrow = u.rowm[ch][lane];
      unsigned int mlo = (unsigned int)myrow, mhi = (unsigned int)(myrow >> 32);
#pragma unroll
      for (int i = 0; i < 64; ++i) {
        unsigned int rlo = (unsigned int)__builtin_amdgcn_readlane((int)mlo, i);
        unsigned int rhi = (unsigned int)__builtin_amdgcn_readlane((int)mhi, i);
        unsigned long long row = ((unsigned long long)rhi << 32) | (unsigned long long)rlo;
        if (!((s >> i) & 1ULL)) s |= row;   // scalar select; symmetry makes this exact
      }
      unsigned long long keepm = ~s;
      unsigned int Lc2 = Lc;
      unsigned int rank = (unsigned int)__popcll(keepm & ((1ULL << lane) - 1ULL));
      if ((keepm >> lane) & 1ULL) Lpos[Lc2 + rank] = (unsigned short)(ch * 64 + lane);
      if (lane == 0) {
        keepw[ch * 2]     = (unsigned int)keepm;
        keepw[ch * 2 + 1] = (unsigned int)(keepm >> 32);
        LcntS = Lc2 + (unsigned int)__popcll(keepm);
      }
    }
    __syncthreads();   // (B) scan writes visible
  }

  // ---- stable partition: kept first (ascending), then unkept (ascending) ----
  if (wv == 0) {
    unsigned int wvv = keepw[lane];
    unsigned int pc = __popc(wvv);
    unsigned int inc = pc;
    for (int d = 1; d < 64; d <<= 1) {
      unsigned int v = __shfl_up(inc, d);
      if (lane >= d) inc += v;
    }
    wpre[lane] = inc - pc;
    if (lane == 63) wpre[64] = inc;
  }
  __syncthreads();
  unsigned int K = wpre[64];
  size_t selOff = (size_t)BATCH * POST_NMS * 2;
  size_t valOff = selOff + (size_t)BATCH * POST_NMS;
#pragma unroll
  for (int r = 0; r < 2; ++r) {
    int p = t + NTHR * r;
    unsigned int w = p >> 5, bit = p & 31;
    unsigned int wvv = keepw[w];
    bool kp = (wvv >> bit) & 1u;
    unsigned int kpref = wpre[w] + __popc(wvv & ((1u << bit) - 1u));
    unsigned int rr = kp ? kpref : (K + ((unsigned int)p - kpref));
    if (rr < POST_NMS) {
      float2 bxo = kp ? box[p] : make_float2(0.0f, 0.0f);
      size_t ob = (size_t)b * POST_NMS + rr;
      out[ob * 2 + 0] = bxo.x;
      out[ob * 2 + 1] = bxo.y;
      out[selOff + ob] = (float)p;          // sel index, exact in f32
      out[valOff + ob] = kp ? 1.0f : 0.0f;  // valid flag
    }
  }
}

extern "C" void kernel_launch(void* const* d_in, const int* in_sizes, int n_in,
                              void* d_out, int out_size, void* d_ws, size_t ws_size,
                              hipStream_t stream) {
  const float* obj    = (const float*)d_in[0];
  const float* delta  = (const float*)d_in[1];
  const float* anchor = (const float*)d_in[2];
  const int*   imgp   = (const int*)d_in[3];
  float* out = (float*)d_out;

  unsigned char* w = (unsigned char*)d_ws;
  unsigned int* hist       = (unsigned int*)(w);
  unsigned int* cnt        = (unsigned int*)(w + OFF_CNT);
  unsigned int* cutb       = (unsigned int*)(w + OFF_CUT);
  unsigned long long* cand = (unsigned long long*)(w + OFF_CAND);

  // zero hist + cnt (ws is NOT re-poisoned between replays; we must re-init)
  hipMemsetAsync(w, 0, OFF_CUT, stream);

  hist_kernel<<<dim3(512), dim3(256), 0, stream>>>(obj, hist);
  cut_kernel<<<dim3(BATCH), dim3(256), 0, stream>>>(hist, cutb);
  collect_kernel<<<dim3(512), dim3(256), 0, stream>>>(obj, cutb, cnt, cand);
  finalize_kernel<<<dim3(BATCH), dim3(NTHR), 0, stream>>>(delta, anchor, imgp, cnt, cand, out);
}

// Round 3
// 161.244 us; speedup vs baseline: 2.3320x; 1.5255x over previous
//
#include <hip/hip_runtime.h>
#include <hip/hip_bf16.h>

#define BATCH   16
#define NELEM   131072
#define PRE_NMS 2048
#define POST_NMS 512
#define NBKT    8192
#define CAP     4096
#define SORT_N  4096
#define NTHR    1024
#define NCH     32

#define OFF_CNT  524288
#define OFF_CUT  524416
#define OFF_CAND 524544

typedef unsigned long long u64;
typedef unsigned int u32;

__device__ __forceinline__ u32 okey_f32(float f) {
  u32 u = __float_as_uint(f);
  return (u & 0x80000000u) ? ~u : (u | 0x80000000u);
}

__global__ void hist_kernel(const float* __restrict__ obj, u32* __restrict__ hist) {
  int b = blockIdx.x >> 5, seg = blockIdx.x & 31;
  __shared__ u32 lh[NBKT];
  for (int i = threadIdx.x; i < NBKT; i += 256) lh[i] = 0u;
  __syncthreads();
  const float* p = obj + (size_t)b * NELEM + (size_t)seg * 4096;
#pragma unroll
  for (int k = 0; k < 16; ++k) {
    float v = p[threadIdx.x + k * 256];
    atomicAdd(&lh[okey_f32(v) >> 19], 1u);
  }
  __syncthreads();
  u32* gh = hist + (size_t)b * NBKT;
  for (int i = threadIdx.x; i < NBKT; i += 256) {
    u32 c = lh[i];
    if (c) atomicAdd(&gh[i], c);
  }
}

__global__ void cut_kernel(const u32* __restrict__ hist, u32* __restrict__ cutb) {
  int b = blockIdx.x, t = threadIdx.x;
  const u32* h = hist + (size_t)b * NBKT;
  u32 loc[32];
  u32 s = 0;
#pragma unroll
  for (int k = 0; k < 32; ++k) { loc[k] = h[t * 32 + k]; s += loc[k]; }
  __shared__ u32 sa[256], sb[256];
  sa[t] = s;
  __syncthreads();
  u32* cur = sa; u32* nxt = sb;
  for (int d = 1; d < 256; d <<= 1) {
    nxt[t] = cur[t] + ((t + d < 256) ? cur[t + d] : 0u);
    __syncthreads();
    u32* tmp = cur; cur = nxt; nxt = tmp;
  }
  u32 above = cur[t] - s;
  u32 run = above;
#pragma unroll
  for (int k = 31; k >= 0; --k) {
    u32 prev = run; run += loc[k];
    if (prev < PRE_NMS && run >= PRE_NMS) cutb[b] = (u32)(t * 32 + k);
  }
}

__global__ void collect_kernel(const float* __restrict__ obj, const u32* __restrict__ cutb,
                               u32* __restrict__ cnt, u64* __restrict__ cand) {
  int b = blockIdx.x >> 5, seg = blockIdx.x & 31;
  __shared__ u64 buf[4096];
  __shared__ u32 lcnt, gbase;
  if (threadIdx.x == 0) lcnt = 0u;
  __syncthreads();
  u32 c = cutb[b];
  const float* p = obj + (size_t)b * NELEM + (size_t)seg * 4096;
#pragma unroll
  for (int k = 0; k < 16; ++k) {
    int li = threadIdx.x + k * 256;
    u32 ok = okey_f32(p[li]);
    if ((ok >> 19) >= c) {
      u32 pos = atomicAdd(&lcnt, 1u);
      buf[pos] = ((u64)(~ok) << 32) | (u32)(seg * 4096 + li);
    }
  }
  __syncthreads();
  if (threadIdx.x == 0) gbase = atomicAdd(&cnt[b], lcnt);
  __syncthreads();
  u64* cb = cand + (size_t)b * CAP;
  u32 n = lcnt, g = gbase;
  for (u32 i = threadIdx.x; i < n; i += 256) {
    u32 d = g + i;
    if (d < CAP) cb[d] = buf[i];
  }
}

// EXACT replacement for: fdiv_rn(inter, max(uni,1e-6)) > 0.5
// fdiv_rn(a,m) > 0.5  <=>  a/m > 0.5 + 2^-25 (ties-to-even keeps 0.5 at the midpoint)
// m*(0.5+2^-25) has <=49 mantissa bits -> exact in double; comparison exact.
__device__ __forceinline__ bool iou_gt(float2 a, float wa, float2 b, float wb) {
  float inter = fmaxf(__fsub_rn(fminf(a.y, b.y), fmaxf(a.x, b.x)), 0.0f);
  float uni = __fsub_rn(__fadd_rn(wa, wb), inter);
  float m = fmaxf(uni, 1e-6f);
  return (double)inter > (double)m * 0x1.000001p-1;
}

__device__ __forceinline__ float2 decode_one(const float2* __restrict__ d2,
                                             const float2* __restrict__ a2,
                                             size_t base, u32 idx, float img) {
  float2 dd = d2[base + idx];
  float2 aa = a2[base + idx];
  float aw = __fsub_rn(aa.y, aa.x);
  float ac = __fadd_rn(aa.x, __fmul_rn(0.5f, aw));
  float dw = fminf(dd.y, 4.0f);
  float pc = __fadd_rn(__fmul_rn(dd.x, aw), ac);
  float pw = __fmul_rn(expf(dw), aw);
  float hx = __fmul_rn(0.5f, pw);
  float x1 = fminf(fmaxf(__fsub_rn(pc, hx), 0.0f), img);
  float x2 = fminf(fmaxf(__fadd_rn(pc, hx), 0.0f), img);
  return make_float2(x1, x2);
}

__device__ __forceinline__ u64 shflx64(u64 v, int j) {
  int lo = __shfl_xor((int)(u32)v, j, 64);
  int hi = __shfl_xor((int)(u32)(v >> 32), j, 64);
  return ((u64)(u32)hi << 32) | (u64)(u32)lo;
}

__device__ __forceinline__ void wave_ce(u64& e, int i, int k, int j, int lane) {
  u64 o = shflx64(e, j);
  bool low = ((lane & j) == 0);
  bool up = ((i & k) == 0);
  u64 mn = (o < e) ? o : e;
  u64 mx = (o < e) ? e : o;
  e = (low == up) ? mn : mx;
}

__device__ __forceinline__ void reg_ce(u64& a, u64& b, bool up) {
  // a holds the lower index element
  u64 mn = (b < a) ? b : a;
  u64 mx = (b < a) ? a : b;
  a = up ? mn : mx;
  b = up ? mx : mn;
}

__device__ __forceinline__ void lds_ce(u64& e, u64 o, bool low, bool up) {
  u64 mn = (o < e) ? o : e;
  u64 mx = (o < e) ? e : o;
  e = (low == up) ? mn : mx;
}

__global__ __launch_bounds__(NTHR) void finalize_kernel(
    const float* __restrict__ delta, const float* __restrict__ anchor,
    const int* __restrict__ imgp,
    const u32* __restrict__ cnt, const u64* __restrict__ cand,
    float* __restrict__ out) {
  __shared__ u64 bufA[SORT_N];                       // 32 KB (sort ping)
  __shared__ union U2 {
    u64 bufB[SORT_N];                                // 32 KB (sort pong)
    float2 Lbox[PRE_NMS];                            // 16 KB (kept boxes, NMS phase)
  } u2;
  __shared__ float2 box[PRE_NMS];                    // 16 KB
  __shared__ u32 keepw[NCH * 2];
  __shared__ u32 wpre[65];
  __shared__ u32 LcntS;

  int b = blockIdx.x, t = threadIdx.x;
  int wv = t >> 6, lane = t & 63;

  u32 C = cnt[b]; if (C > SORT_N) C = SORT_N;
  const u64* cb = cand + (size_t)b * CAP;
  u64 e0 = ((u32)t < C) ? cb[t] : ~0ull;
  u64 e1 = ((u32)(t + 1024) < C) ? cb[t + 1024] : ~0ull;
  u64 e2 = ((u32)(t + 2048) < C) ? cb[t + 2048] : ~0ull;
  u64 e3 = ((u32)(t + 3072) < C) ? cb[t + 3072] : ~0ull;

  // ---- bitonic sort, elements in registers; i = r*1024 + t ----
  for (int k = 2; k <= 64; k <<= 1)
    for (int j = k >> 1; j >= 1; j >>= 1) {
      wave_ce(e0, t, k, j, lane);
      wave_ce(e1, t + 1024, k, j, lane);
      wave_ce(e2, t + 2048, k, j, lane);
      wave_ce(e3, t + 3072, k, j, lane);
    }
  int pp = 0;
  for (int k = 128; k <= SORT_N; k <<= 1) {
    for (int j = k >> 1; j >= 64; j >>= 1) {
      if (j == 2048) {
        reg_ce(e0, e2, ((t) & k) == 0);
        reg_ce(e1, e3, ((t + 1024) & k) == 0);
      } else if (j == 1024) {
        reg_ce(e0, e1, ((t) & k) == 0);
        reg_ce(e2, e3, ((t + 2048) & k) == 0);
      } else {
        u64* buf = (pp & 1) ? u2.bufB : bufA; ++pp;
        buf[t] = e0; buf[t + 1024] = e1; buf[t + 2048] = e2; buf[t + 3072] = e3;
        __syncthreads();
        u64 o0 = buf[t ^ j];
        u64 o1 = buf[(t + 1024) ^ j];
        u64 o2 = buf[(t + 2048) ^ j];
        u64 o3 = buf[(t + 3072) ^ j];
        bool low = ((t & j) == 0);
        lds_ce(e0, o0, low, ((t) & k) == 0);
        lds_ce(e1, o1, low, ((t + 1024) & k) == 0);
        lds_ce(e2, o2, low, ((t + 2048) & k) == 0);
        lds_ce(e3, o3, low, ((t + 3072) & k) == 0);
      }
    }
    for (int j = 32; j >= 1; j >>= 1) {
      wave_ce(e0, t, k, j, lane);
      wave_ce(e1, t + 1024, k, j, lane);
      wave_ce(e2, t + 2048, k, j, lane);
      wave_ce(e3, t + 3072, k, j, lane);
    }
  }
  // e0 = sorted element t, e1 = sorted element t+1024 (the top-2048 in order)

  // ---- decode + clip; thread owns candidates t (bx0) and t+1024 (bx1) ----
  int iv = imgp[0];
  float img = (iv > 0 && iv < 1000000) ? (float)iv : __int_as_float(iv);
  const float2* d2 = (const float2*)delta;
  const float2* a2 = (const float2*)anchor;
  size_t base = (size_t)b * NELEM;
  float2 bx0 = decode_one(d2, a2, base, (u32)e0, img);
  float2 bx1 = decode_one(d2, a2, base, (u32)e1, img);
  float wa0 = __fsub_rn(bx0.y, bx0.x);
  float wa1 = __fsub_rn(bx1.y, bx1.x);
  bool sup0 = false, sup1 = false;
  box[t] = bx0;
  box[t + 1024] = bx1;
  if (t == 0) LcntS = 0u;
  __syncthreads();

  // ---- in-chunk 64x64 adjacency rows, kept in registers ----
  // thread (wv,lane) holds row `lane` of chunk wv (m0) and chunk wv+16 (m1)
  u64 m0 = 0ull, m1 = 0ull;
  {
    int c0 = wv * 64, c1 = (wv + 16) * 64;
    for (int j = 0; j < 64; ++j) {
      float2 bb0 = box[c0 + j];
      float2 bb1 = box[c1 + j];
      float w0 = __fsub_rn(bb0.y, bb0.x);
      float w1 = __fsub_rn(bb1.y, bb1.x);
      if ((j != lane) & iou_gt(bx0, wa0, bb0, w0)) m0 |= 1ull << j;
      if ((j != lane) & iou_gt(bx1, wa1, bb1, w1)) m1 |= 1ull << j;
    }
  }

  // ---- greedy NMS over 32 chunks ----
  u32 updL = 0;
  for (int ch = 0; ch < NCH; ++ch) {
    u32 Lc = LcntS;
    for (u32 l = updL; l < Lc; ++l) {              // incremental cross-chunk update
      float2 bi = u2.Lbox[l];
      float wb = __fsub_rn(bi.y, bi.x);
      sup0 = sup0 | iou_gt(bx0, wa0, bi, wb);
      sup1 = sup1 | iou_gt(bx1, wa1, bi, wb);
    }
    updL = Lc;
    __syncthreads();                                // update done; old Lbox reads done
    if (wv == (ch & 15)) {
      bool mysup = (ch < 16) ? sup0 : sup1;
      u64 myrow = (ch < 16) ? m0 : m1;
      u64 s = __ballot(mysup);
      u64 rem = ~s;
      u64 kept = 0ull;
      u32 mlo = (u32)myrow, mhi = (u32)(myrow >> 32);
      while (rem) {                                 // visit kept candidates only
        int i = __builtin_ctzll(rem);
        kept |= 1ull << i;
        u32 rlo = (u32)__builtin_amdgcn_readlane((int)mlo, i);
        u32 rhi = (u32)__builtin_amdgcn_readlane((int)mhi, i);
        u64 row = ((u64)rhi << 32) | (u64)rlo;
        rem &= ~(row | (1ull << i));
      }
      float2 myb = (ch < 16) ? bx0 : bx1;
      u32 rank = (u32)__popcll(kept & ((1ull << lane) - 1ull));
      if ((kept >> lane) & 1ull) u2.Lbox[Lc + rank] = myb;   // append kept boxes
      if (lane == 0) {
        keepw[ch * 2]     = (u32)kept;
        keepw[ch * 2 + 1] = (u32)(kept >> 32);
        LcntS = Lc + (u32)__popcll(kept);
      }
    }
    __syncthreads();                                // scan writes visible
  }

  // ---- stable partition: kept first (ascending), then unkept (ascending) ----
  if (wv == 0) {
    u32 wvv = keepw[lane];
    u32 pc = __popc(wvv);
    u32 inc = pc;
    for (int d = 1; d < 64; d <<= 1) {
      u32 v = __shfl_up(inc, d);
      if (lane >= d) inc += v;
    }
    wpre[lane] = inc - pc;
    if (lane == 63) wpre[64] = inc;
  }
  __syncthreads();
  u32 K = wpre[64];
  size_t selOff = (size_t)BATCH * POST_NMS * 2;
  size_t valOff = selOff + (size_t)BATCH * POST_NMS;
#pragma unroll
  for (int r = 0; r < 2; ++r) {
    int p = t + NTHR * r;
    u32 w = p >> 5, bit = p & 31;
    u32 wvv = keepw[w];
    bool kp = (wvv >> bit) & 1u;
    u32 kpref = wpre[w] + __popc(wvv & ((1u << bit) - 1u));
    u32 rr = kp ? kpref : (K + ((u32)p - kpref));
    if (rr < POST_NMS) {
      float2 bxo = kp ? box[p] : make_float2(0.0f, 0.0f);
      size_t ob = (size_t)b * POST_NMS + rr;
      out[ob * 2 + 0] = bxo.x;
      out[ob * 2 + 1] = bxo.y;
      out[selOff + ob] = (float)p;
      out[valOff + ob] = kp ? 1.0f : 0.0f;
    }
  }
}

extern "C" void kernel_launch(void* const* d_in, const int* in_sizes, int n_in,
                              void* d_out, int out_size, void* d_ws, size_t ws_size,
                              hipStream_t stream) {
  const float* obj    = (const float*)d_in[0];
  const float* delta  = (const float*)d_in[1];
  const float* anchor = (const float*)d_in[2];
  const int*   imgp   = (const int*)d_in[3];
  float* out = (float*)d_out;

  unsigned char* w = (unsigned char*)d_ws;
  u32* hist = (u32*)(w);
  u32* cnt  = (u32*)(w + OFF_CNT);
  u32* cutb = (u32*)(w + OFF_CUT);
  u64* cand = (u64*)(w + OFF_CAND);

  hipMemsetAsync(w, 0, OFF_CUT, stream);   // re-init hist+cnt every call

  hist_kernel<<<dim3(512), dim3(256), 0, stream>>>(obj, hist);
  cut_kernel<<<dim3(BATCH), dim3(256), 0, stream>>>(hist, cutb);
  collect_kernel<<<dim3(512), dim3(256), 0, stream>>>(obj, cutb, cnt, cand);
  finalize_kernel<<<dim3(BATCH), dim3(NTHR), 0, stream>>>(delta, anchor, imgp, cnt, cand, out);
}

// Round 4
// 132.469 us; speedup vs baseline: 2.8386x; 1.2172x over previous
//
#include <hip/hip_runtime.h>
#include <hip/hip_bf16.h>

#define BATCH   16
#define NELEM   131072
#define PRE_NMS 2048
#define POST_NMS 512
#define NBKT    8192
#define CAP     4096
#define SORT_N  4096
#define NTHR    1024
#define NCH     32

#define OFF_CNT  524288
#define OFF_CUT  524416
#define OFF_CAND 524544

typedef unsigned long long u64;
typedef unsigned int u32;

__device__ __forceinline__ u32 okey_f32(float f) {
  u32 u = __float_as_uint(f);
  return (u & 0x80000000u) ? ~u : (u | 0x80000000u);
}

__global__ void hist_kernel(const float* __restrict__ obj, u32* __restrict__ hist) {
  int b = blockIdx.x >> 5, seg = blockIdx.x & 31;
  __shared__ u32 lh[NBKT];
  for (int i = threadIdx.x; i < NBKT; i += 256) lh[i] = 0u;
  __syncthreads();
  const float* p = obj + (size_t)b * NELEM + (size_t)seg * 4096;
#pragma unroll
  for (int k = 0; k < 16; ++k) {
    float v = p[threadIdx.x + k * 256];
    atomicAdd(&lh[okey_f32(v) >> 19], 1u);
  }
  __syncthreads();
  u32* gh = hist + (size_t)b * NBKT;
  for (int i = threadIdx.x; i < NBKT; i += 256) {
    u32 c = lh[i];
    if (c) atomicAdd(&gh[i], c);
  }
}

__global__ void cut_kernel(const u32* __restrict__ hist, u32* __restrict__ cutb) {
  int b = blockIdx.x, t = threadIdx.x;
  const u32* h = hist + (size_t)b * NBKT;
  u32 loc[32];
  u32 s = 0;
#pragma unroll
  for (int k = 0; k < 32; ++k) { loc[k] = h[t * 32 + k]; s += loc[k]; }
  __shared__ u32 sa[256], sb[256];
  sa[t] = s;
  __syncthreads();
  u32* cur = sa; u32* nxt = sb;
  for (int d = 1; d < 256; d <<= 1) {
    nxt[t] = cur[t] + ((t + d < 256) ? cur[t + d] : 0u);
    __syncthreads();
    u32* tmp = cur; cur = nxt; nxt = tmp;
  }
  u32 above = cur[t] - s;
  u32 run = above;
#pragma unroll
  for (int k = 31; k >= 0; --k) {
    u32 prev = run; run += loc[k];
    if (prev < PRE_NMS && run >= PRE_NMS) cutb[b] = (u32)(t * 32 + k);
  }
}

__global__ void collect_kernel(const float* __restrict__ obj, const u32* __restrict__ cutb,
                               u32* __restrict__ cnt, u64* __restrict__ cand) {
  int b = blockIdx.x >> 5, seg = blockIdx.x & 31;
  __shared__ u64 buf[4096];
  __shared__ u32 lcnt, gbase;
  if (threadIdx.x == 0) lcnt = 0u;
  __syncthreads();
  u32 c = cutb[b];
  const float* p = obj + (size_t)b * NELEM + (size_t)seg * 4096;
#pragma unroll
  for (int k = 0; k < 16; ++k) {
    int li = threadIdx.x + k * 256;
    u32 ok = okey_f32(p[li]);
    if ((ok >> 19) >= c) {
      u32 pos = atomicAdd(&lcnt, 1u);
      buf[pos] = ((u64)(~ok) << 32) | (u32)(seg * 4096 + li);
    }
  }
  __syncthreads();
  if (threadIdx.x == 0) gbase = atomicAdd(&cnt[b], lcnt);
  __syncthreads();
  u64* cb = cand + (size_t)b * CAP;
  u32 n = lcnt, g = gbase;
  for (u32 i = threadIdx.x; i < n; i += 256) {
    u32 d = g + i;
    if (d < CAP) cb[d] = buf[i];
  }
}

// EXACT f32-only replacement for: fdiv_rn(max(i,0), max(uni,1e-6)) > 0.5
// fdiv_rn(i,m) > 0.5  <=>  real i/m > 0.5+2^-25 (tie-to-even at the midpoint keeps 0.5)
//                     <=>  i > m*(0.5+2^-25) = h*(1+2^-24),  h = 0.5*m exact in f32.
// Any f32 i > h satisfies i >= h+ulp(h) > h*(1+2^-24); any i <= h fails. So the
// f32 compare i > 0.5f*m is bit-identical. The i<0 (no-overlap) case is false
// under both formulations, so the max(i,0) clamp may be dropped.
__device__ __forceinline__ bool iou_gt(float2 a, float wa, float2 b, float wb) {
  float i = __fsub_rn(fminf(a.y, b.y), fmaxf(a.x, b.x));
  float uni = __fsub_rn(__fadd_rn(wa, wb), i);
  return i > __fmul_rn(0.5f, fmaxf(uni, 1e-6f));
}

__device__ __forceinline__ float2 decode_one(const float2* __restrict__ d2,
                                             const float2* __restrict__ a2,
                                             size_t base, u32 idx, float img) {
  float2 dd = d2[base + idx];
  float2 aa = a2[base + idx];
  float aw = __fsub_rn(aa.y, aa.x);
  float ac = __fadd_rn(aa.x, __fmul_rn(0.5f, aw));
  float dw = fminf(dd.y, 4.0f);
  float pc = __fadd_rn(__fmul_rn(dd.x, aw), ac);
  float pw = __fmul_rn(expf(dw), aw);
  float hx = __fmul_rn(0.5f, pw);
  float x1 = fminf(fmaxf(__fsub_rn(pc, hx), 0.0f), img);
  float x2 = fminf(fmaxf(__fadd_rn(pc, hx), 0.0f), img);
  return make_float2(x1, x2);
}

__device__ __forceinline__ u64 shflx64(u64 v, int j) {
  int lo = __shfl_xor((int)(u32)v, j, 64);
  int hi = __shfl_xor((int)(u32)(v >> 32), j, 64);
  return ((u64)(u32)hi << 32) | (u64)(u32)lo;
}

__device__ __forceinline__ void wave_ce(u64& e, int i, int k, int j, int lane) {
  u64 o = shflx64(e, j);
  bool low = ((lane & j) == 0);
  bool up = ((i & k) == 0);
  u64 mn = (o < e) ? o : e;
  u64 mx = (o < e) ? e : o;
  e = (low == up) ? mn : mx;
}

__device__ __forceinline__ void reg_ce(u64& a, u64& b, bool up) {
  u64 mn = (b < a) ? b : a;
  u64 mx = (b < a) ? a : b;
  a = up ? mn : mx;
  b = up ? mx : mn;
}

__device__ __forceinline__ void lds_ce(u64& e, u64 o, bool low, bool up) {
  u64 mn = (o < e) ? o : e;
  u64 mx = (o < e) ? e : o;
  e = (low == up) ? mn : mx;
}

__global__ __launch_bounds__(NTHR) void finalize_kernel(
    const float* __restrict__ delta, const float* __restrict__ anchor,
    const int* __restrict__ imgp,
    const u32* __restrict__ cnt, const u64* __restrict__ cand,
    float* __restrict__ out) {
  __shared__ u64 bufA[SORT_N];                       // 32 KB (sort ping)
  __shared__ union U2 {
    u64 bufB[SORT_N];                                // 32 KB (sort pong)
    float2 Lbox[PRE_NMS];                            // 16 KB (kept boxes, NMS phase)
  } u2;
  __shared__ float2 box[PRE_NMS];                    // 16 KB
  __shared__ u32 keepw[NCH * 2];
  __shared__ u32 wpre[65];
  __shared__ u32 LcntS;

  int b = blockIdx.x, t = threadIdx.x;
  int wv = t >> 6, lane = t & 63;

  u32 C = cnt[b]; if (C > SORT_N) C = SORT_N;
  const u64* cb = cand + (size_t)b * CAP;
  u64 e0 = ((u32)t < C) ? cb[t] : ~0ull;
  u64 e1 = ((u32)(t + 1024) < C) ? cb[t + 1024] : ~0ull;
  u64 e2 = ((u32)(t + 2048) < C) ? cb[t + 2048] : ~0ull;
  u64 e3 = ((u32)(t + 3072) < C) ? cb[t + 3072] : ~0ull;

  // ---- bitonic sort, elements in registers; element index i = r*1024 + t ----
  for (int k = 2; k <= 64; k <<= 1)
    for (int j = k >> 1; j >= 1; j >>= 1) {
      wave_ce(e0, t, k, j, lane);
      wave_ce(e1, t + 1024, k, j, lane);
      wave_ce(e2, t + 2048, k, j, lane);
      wave_ce(e3, t + 3072, k, j, lane);
    }
  int pp = 0;
  for (int k = 128; k <= SORT_N; k <<= 1) {
    for (int j = k >> 1; j >= 64; j >>= 1) {
      if (j == 2048) {
        reg_ce(e0, e2, ((t) & k) == 0);
        reg_ce(e1, e3, ((t + 1024) & k) == 0);
      } else if (j == 1024) {
        reg_ce(e0, e1, ((t) & k) == 0);
        reg_ce(e2, e3, ((t + 2048) & k) == 0);
      } else {
        u64* buf = (pp & 1) ? u2.bufB : bufA; ++pp;
        buf[t] = e0; buf[t + 1024] = e1; buf[t + 2048] = e2; buf[t + 3072] = e3;
        __syncthreads();
        u64 o0 = buf[t ^ j];
        u64 o1 = buf[(t + 1024) ^ j];
        u64 o2 = buf[(t + 2048) ^ j];
        u64 o3 = buf[(t + 3072) ^ j];
        bool low = ((t & j) == 0);
        lds_ce(e0, o0, low, ((t) & k) == 0);
        lds_ce(e1, o1, low, ((t + 1024) & k) == 0);
        lds_ce(e2, o2, low, ((t + 2048) & k) == 0);
        lds_ce(e3, o3, low, ((t + 3072) & k) == 0);
        __syncthreads();
      }
    }
    for (int j = 32; j >= 1; j >>= 1) {
      wave_ce(e0, t, k, j, lane);
      wave_ce(e1, t + 1024, k, j, lane);
      wave_ce(e2, t + 2048, k, j, lane);
      wave_ce(e3, t + 3072, k, j, lane);
    }
  }
  // e0 = sorted element t, e1 = sorted element t+1024 (top-2048 in order)

  // ---- decode + clip; thread owns candidates t (bx0) and t+1024 (bx1) ----
  int iv = imgp[0];
  float img = (iv > 0 && iv < 1000000) ? (float)iv : __int_as_float(iv);
  const float2* d2 = (const float2*)delta;
  const float2* a2 = (const float2*)anchor;
  size_t base = (size_t)b * NELEM;
  float2 bx0 = decode_one(d2, a2, base, (u32)e0, img);
  float2 bx1 = decode_one(d2, a2, base, (u32)e1, img);
  float wa0 = __fsub_rn(bx0.y, bx0.x);
  float wa1 = __fsub_rn(bx1.y, bx1.x);
  bool sup0 = false, sup1 = false;
  box[t] = bx0;
  box[t + 1024] = bx1;
  if (t == 0) LcntS = 0u;
  __syncthreads();

  // ---- in-chunk 64x64 adjacency rows, kept in registers ----
  u64 m0 = 0ull, m1 = 0ull;
  {
    int c0 = wv * 64, c1 = (wv + 16) * 64;
    for (int j = 0; j < 64; ++j) {
      float2 bb0 = box[c0 + j];
      float2 bb1 = box[c1 + j];
      float w0 = __fsub_rn(bb0.y, bb0.x);
      float w1 = __fsub_rn(bb1.y, bb1.x);
      if ((j != lane) & iou_gt(bx0, wa0, bb0, w0)) m0 |= 1ull << j;
      if ((j != lane) & iou_gt(bx1, wa1, bb1, w1)) m1 |= 1ull << j;
    }
  }

  // ---- greedy NMS over 32 chunks; ONE barrier per chunk ----
  // Appends write Lbox[Lc..), readers touch [0,LcSnapshot) — disjoint. The
  // threadfence orders appends before the LcntS bump, so a reader seeing the
  // new count also sees the data (early extra processing is a harmless OR).
  u32 updL = 0;
  for (int ch = 0; ch < NCH; ++ch) {
    u32 Lc = LcntS;
    // dead-work elimination: sup0 is consumed at iteration wv, sup1 at wv+16.
    if (ch <= wv) {
      for (u32 l = updL; l < Lc; ++l) {
        float2 bi = u2.Lbox[l];
        float wb_ = __fsub_rn(bi.y, bi.x);
        sup0 = sup0 | iou_gt(bx0, wa0, bi, wb_);
        sup1 = sup1 | iou_gt(bx1, wa1, bi, wb_);
      }
    } else if (ch <= wv + 16) {
      for (u32 l = updL; l < Lc; ++l) {
        float2 bi = u2.Lbox[l];
        float wb_ = __fsub_rn(bi.y, bi.x);
        sup1 = sup1 | iou_gt(bx1, wa1, bi, wb_);
      }
    }
    updL = Lc;
    if (wv == (ch & 15)) {
      bool mysup = (ch < 16) ? sup0 : sup1;
      u64 myrow = (ch < 16) ? m0 : m1;
      u64 s = __ballot(mysup);
      u64 rem = ~s;
      u64 kept = 0ull;
      u32 mlo = (u32)myrow, mhi = (u32)(myrow >> 32);
      while (rem) {
        int i = __builtin_ctzll(rem);
        kept |= 1ull << i;
        u32 rlo = (u32)__builtin_amdgcn_readlane((int)mlo, i);
        u32 rhi = (u32)__builtin_amdgcn_readlane((int)mhi, i);
        u64 row = ((u64)rhi << 32) | (u64)rlo;
        rem &= ~(row | (1ull << i));
      }
      float2 myb = (ch < 16) ? bx0 : bx1;
      u32 rank = (u32)__popcll(kept & ((1ull << lane) - 1ull));
      if ((kept >> lane) & 1ull) u2.Lbox[Lc + rank] = myb;
      __threadfence_block();
      if (lane == 0) {
        keepw[ch * 2]     = (u32)kept;
        keepw[ch * 2 + 1] = (u32)(kept >> 32);
        LcntS = Lc + (u32)__popcll(kept);
      }
    }
    __syncthreads();
  }

  // ---- stable partition: kept first (ascending), then unkept (ascending) ----
  if (wv == 0) {
    u32 wvv = keepw[lane];
    u32 pc = __popc(wvv);
    u32 inc = pc;
    for (int d = 1; d < 64; d <<= 1) {
      u32 v = __shfl_up(inc, d);
      if (lane >= d) inc += v;
    }
    wpre[lane] = inc - pc;
    if (lane == 63) wpre[64] = inc;
  }
  __syncthreads();
  u32 K = wpre[64];
  size_t selOff = (size_t)BATCH * POST_NMS * 2;
  size_t valOff = selOff + (size_t)BATCH * POST_NMS;
#pragma unroll
  for (int r = 0; r < 2; ++r) {
    int p = t + NTHR * r;
    u32 w = p >> 5, bit = p & 31;
    u32 wvv = keepw[w];
    bool kp = (wvv >> bit) & 1u;
    u32 kpref = wpre[w] + __popc(wvv & ((1u << bit) - 1u));
    u32 rr = kp ? kpref : (K + ((u32)p - kpref));
    if (rr < POST_NMS) {
      float2 bxo = kp ? box[p] : make_float2(0.0f, 0.0f);
      size_t ob = (size_t)b * POST_NMS + rr;
      out[ob * 2 + 0] = bxo.x;
      out[ob * 2 + 1] = bxo.y;
      out[selOff + ob] = (float)p;
      out[valOff + ob] = kp ? 1.0f : 0.0f;
    }
  }
}

extern "C" void kernel_launch(void* const* d_in, const int* in_sizes, int n_in,
                              void* d_out, int out_size, void* d_ws, size_t ws_size,
                              hipStream_t stream) {
  const float* obj    = (const float*)d_in[0];
  const float* delta  = (const float*)d_in[1];
  const float* anchor = (const float*)d_in[2];
  const int*   imgp   = (const int*)d_in[3];
  float* out = (float*)d_out;

  unsigned char* w = (unsigned char*)d_ws;
  u32* hist = (u32*)(w);
  u32* cnt  = (u32*)(w + OFF_CNT);
  u32* cutb = (u32*)(w + OFF_CUT);
  u64* cand = (u64*)(w + OFF_CAND);

  hipMemsetAsync(w, 0, OFF_CUT, stream);   // re-init hist+cnt every call

  hist_kernel<<<dim3(512), dim3(256), 0, stream>>>(obj, hist);
  cut_kernel<<<dim3(BATCH), dim3(256), 0, stream>>>(hist, cutb);
  collect_kernel<<<dim3(512), dim3(256), 0, stream>>>(obj, cutb, cnt, cand);
  finalize_kernel<<<dim3(BATCH), dim3(NTHR), 0, stream>>>(delta, anchor, imgp, cnt, cand, out);
}

// Round 5
// 118.143 us; speedup vs baseline: 3.1828x; 1.1213x over previous
//
#include <hip/hip_runtime.h>
#include <hip/hip_bf16.h>

#define BATCH   16
#define NELEM   131072
#define PRE_NMS 2048
#define POST_NMS 512
#define NBKT    8192
#define CAP     4096
#define SORT_N  4096
#define NTHR    1024
#define NCH     32
#define NSB     256      // spatial center bins

#define OFF_CNT  524288
#define OFF_CUT  524416
#define OFF_CAND 524544

typedef unsigned long long u64;
typedef unsigned int u32;
typedef unsigned short u16;

__device__ __forceinline__ u32 okey_f32(float f) {
  u32 u = __float_as_uint(f);
  return (u & 0x80000000u) ? ~u : (u | 0x80000000u);
}

__global__ void hist_kernel(const float* __restrict__ obj, u32* __restrict__ hist) {
  int b = blockIdx.x >> 5, seg = blockIdx.x & 31;
  __shared__ u32 lh[NBKT];
  for (int i = threadIdx.x; i < NBKT; i += 256) lh[i] = 0u;
  __syncthreads();
  const float* p = obj + (size_t)b * NELEM + (size_t)seg * 4096;
#pragma unroll
  for (int k = 0; k < 16; ++k) {
    float v = p[threadIdx.x + k * 256];
    atomicAdd(&lh[okey_f32(v) >> 19], 1u);
  }
  __syncthreads();
  u32* gh = hist + (size_t)b * NBKT;
  for (int i = threadIdx.x; i < NBKT; i += 256) {
    u32 c = lh[i];
    if (c) atomicAdd(&gh[i], c);
  }
}

__global__ void cut_kernel(const u32* __restrict__ hist, u32* __restrict__ cutb) {
  int b = blockIdx.x, t = threadIdx.x;
  const u32* h = hist + (size_t)b * NBKT;
  u32 loc[32];
  u32 s = 0;
#pragma unroll
  for (int k = 0; k < 32; ++k) { loc[k] = h[t * 32 + k]; s += loc[k]; }
  __shared__ u32 sa[256], sb[256];
  sa[t] = s;
  __syncthreads();
  u32* cur = sa; u32* nxt = sb;
  for (int d = 1; d < 256; d <<= 1) {
    nxt[t] = cur[t] + ((t + d < 256) ? cur[t + d] : 0u);
    __syncthreads();
    u32* tmp = cur; cur = nxt; nxt = tmp;
  }
  u32 above = cur[t] - s;
  u32 run = above;
#pragma unroll
  for (int k = 31; k >= 0; --k) {
    u32 prev = run; run += loc[k];
    if (prev < PRE_NMS && run >= PRE_NMS) cutb[b] = (u32)(t * 32 + k);
  }
}

__global__ void collect_kernel(const float* __restrict__ obj, const u32* __restrict__ cutb,
                               u32* __restrict__ cnt, u64* __restrict__ cand) {
  int b = blockIdx.x >> 5, seg = blockIdx.x & 31;
  __shared__ u64 buf[4096];
  __shared__ u32 lcnt, gbase;
  if (threadIdx.x == 0) lcnt = 0u;
  __syncthreads();
  u32 c = cutb[b];
  const float* p = obj + (size_t)b * NELEM + (size_t)seg * 4096;
#pragma unroll
  for (int k = 0; k < 16; ++k) {
    int li = threadIdx.x + k * 256;
    u32 ok = okey_f32(p[li]);
    if ((ok >> 19) >= c) {
      u32 pos = atomicAdd(&lcnt, 1u);
      buf[pos] = ((u64)(~ok) << 32) | (u32)(seg * 4096 + li);
    }
  }
  __syncthreads();
  if (threadIdx.x == 0) gbase = atomicAdd(&cnt[b], lcnt);
  __syncthreads();
  u64* cb = cand + (size_t)b * CAP;
  u32 n = lcnt, g = gbase;
  for (u32 i = threadIdx.x; i < n; i += 256) {
    u32 d = g + i;
    if (d < CAP) cb[d] = buf[i];
  }
}

// EXACT f32-only replacement for: fdiv_rn(max(i,0), max(uni,1e-6)) > 0.5
// (proof in R3/R4: i > 0.5f*max(uni,1e-6) is bit-identical to the reference)
__device__ __forceinline__ bool iou_gt(float2 a, float wa, float2 b, float wb) {
  float i = __fsub_rn(fminf(a.y, b.y), fmaxf(a.x, b.x));
  float uni = __fsub_rn(__fadd_rn(wa, wb), i);
  return i > __fmul_rn(0.5f, fmaxf(uni, 1e-6f));
}

__device__ __forceinline__ float2 decode_one(const float2* __restrict__ d2,
                                             const float2* __restrict__ a2,
                                             size_t base, u32 idx, float img) {
  float2 dd = d2[base + idx];
  float2 aa = a2[base + idx];
  float aw = __fsub_rn(aa.y, aa.x);
  float ac = __fadd_rn(aa.x, __fmul_rn(0.5f, aw));
  float dw = fminf(dd.y, 4.0f);
  float pc = __fadd_rn(__fmul_rn(dd.x, aw), ac);
  float pw = __fmul_rn(expf(dw), aw);
  float hx = __fmul_rn(0.5f, pw);
  float x1 = fminf(fmaxf(__fsub_rn(pc, hx), 0.0f), img);
  float x2 = fminf(fmaxf(__fadd_rn(pc, hx), 0.0f), img);
  return make_float2(x1, x2);
}

__device__ __forceinline__ u64 shflx64(u64 v, int j) {
  int lo = __shfl_xor((int)(u32)v, j, 64);
  int hi = __shfl_xor((int)(u32)(v >> 32), j, 64);
  return ((u64)(u32)hi << 32) | (u64)(u32)lo;
}

__device__ __forceinline__ void wave_ce(u64& e, int i, int k, int j, int lane) {
  u64 o = shflx64(e, j);
  bool low = ((lane & j) == 0);
  bool up = ((i & k) == 0);
  u64 mn = (o < e) ? o : e;
  u64 mx = (o < e) ? e : o;
  e = (low == up) ? mn : mx;
}

__device__ __forceinline__ void reg_ce(u64& a, u64& b, bool up) {
  u64 mn = (b < a) ? b : a;
  u64 mx = (b < a) ? a : b;
  a = up ? mn : mx;
  b = up ? mx : mn;
}

__device__ __forceinline__ void lds_ce(u64& e, u64 o, bool low, bool up) {
  u64 mn = (o < e) ? o : e;
  u64 mx = (o < e) ? e : o;
  e = (low == up) ? mn : mx;
}

struct NmsSh {
  u16 cpos[PRE_NMS];       // candidates sorted by center bin
  u32 bincnt[NSB];
  u32 binstart[NSB + 1];
  u32 binfill[NSB];
  u32 supm[64];            // suppression bitmask over 2048 candidates
  float2 wbox[64];         // newly kept boxes of current chunk
  u32 wrange[64];          // packed (lo<<16)|hi cpos-range per kept box
  u32 nkeptS;
  u32 LcntS;
};

__global__ __launch_bounds__(NTHR) void finalize_kernel(
    const float* __restrict__ delta, const float* __restrict__ anchor,
    const int* __restrict__ imgp,
    const u32* __restrict__ cnt, const u64* __restrict__ cand,
    float* __restrict__ out) {
  __shared__ union UA { u64 sortA[SORT_N]; NmsSh n; } uA;   // 32 KB
  __shared__ u64 bufB[SORT_N];                              // 32 KB
  __shared__ float2 box[PRE_NMS];                           // 16 KB
  __shared__ u32 keepw[NCH * 2];
  __shared__ u32 wpre[65];

  int b = blockIdx.x, t = threadIdx.x;
  int wv = t >> 6, lane = t & 63;

  u32 C = cnt[b]; if (C > SORT_N) C = SORT_N;
  const u64* cb = cand + (size_t)b * CAP;
  u64 e0 = ((u32)t < C) ? cb[t] : ~0ull;
  u64 e1 = ((u32)(t + 1024) < C) ? cb[t + 1024] : ~0ull;
  u64 e2 = ((u32)(t + 2048) < C) ? cb[t + 2048] : ~0ull;
  u64 e3 = ((u32)(t + 3072) < C) ? cb[t + 3072] : ~0ull;

  // ---- bitonic sort, elements in registers; element index i = r*1024 + t ----
  for (int k = 2; k <= 64; k <<= 1)
    for (int j = k >> 1; j >= 1; j >>= 1) {
      wave_ce(e0, t, k, j, lane);
      wave_ce(e1, t + 1024, k, j, lane);
      wave_ce(e2, t + 2048, k, j, lane);
      wave_ce(e3, t + 3072, k, j, lane);
    }
  int pp = 0;
  for (int k = 128; k <= SORT_N; k <<= 1) {
    for (int j = k >> 1; j >= 64; j >>= 1) {
      if (j == 2048) {
        reg_ce(e0, e2, ((t) & k) == 0);
        reg_ce(e1, e3, ((t + 1024) & k) == 0);
      } else if (j == 1024) {
        reg_ce(e0, e1, ((t) & k) == 0);
        reg_ce(e2, e3, ((t + 2048) & k) == 0);
      } else {
        u64* buf = (pp & 1) ? bufB : uA.sortA; ++pp;
        buf[t] = e0; buf[t + 1024] = e1; buf[t + 2048] = e2; buf[t + 3072] = e3;
        __syncthreads();
        u64 o0 = buf[t ^ j];
        u64 o1 = buf[(t + 1024) ^ j];
        u64 o2 = buf[(t + 2048) ^ j];
        u64 o3 = buf[(t + 3072) ^ j];
        bool low = ((t & j) == 0);
        lds_ce(e0, o0, low, ((t) & k) == 0);
        lds_ce(e1, o1, low, ((t + 1024) & k) == 0);
        lds_ce(e2, o2, low, ((t + 2048) & k) == 0);
        lds_ce(e3, o3, low, ((t + 3072) & k) == 0);
        // no trailing barrier needed: next LDS pass uses the other buffer,
        // and its mid-pass barrier orders reads-here before writes-there-after.
      }
    }
    for (int j = 32; j >= 1; j >>= 1) {
      wave_ce(e0, t, k, j, lane);
      wave_ce(e1, t + 1024, k, j, lane);
      wave_ce(e2, t + 2048, k, j, lane);
      wave_ce(e3, t + 3072, k, j, lane);
    }
  }
  __syncthreads();   // last sortA readers done before NmsSh overlay writes

  // ---- decode + clip; thread owns candidates t (bx0, chunk wv) and t+1024 (bx1, chunk wv+16)
  int iv = imgp[0];
  float img = (iv > 0 && iv < 1000000) ? (float)iv : __int_as_float(iv);
  float sbin = (float)NSB / img;
  const float2* d2 = (const float2*)delta;
  const float2* a2 = (const float2*)anchor;
  size_t base = (size_t)b * NELEM;
  float2 bx0 = decode_one(d2, a2, base, (u32)e0, img);
  float2 bx1 = decode_one(d2, a2, base, (u32)e1, img);
  float wa0 = __fsub_rn(bx0.y, bx0.x);
  float wa1 = __fsub_rn(bx1.y, bx1.x);
  box[t] = bx0;
  box[t + 1024] = bx1;
  // zero the spatial/NMS state
  if (t < NSB) { uA.n.bincnt[t] = 0u; uA.n.binfill[t] = 0u; }
  if (t < 64) uA.n.supm[t] = 0u;
  if (t == 0) uA.n.LcntS = 0u;
  float ca0 = __fmul_rn(0.5f, __fadd_rn(bx0.x, bx0.y));
  float ca1 = __fmul_rn(0.5f, __fadd_rn(bx1.x, bx1.y));
  int bi0 = (int)(ca0 * sbin); if (bi0 > NSB - 1) bi0 = NSB - 1;
  int bi1 = (int)(ca1 * sbin); if (bi1 > NSB - 1) bi1 = NSB - 1;
  __syncthreads();

  // ---- spatial counting sort of candidate centers into 256 bins ----
  atomicAdd(&uA.n.bincnt[bi0], 1u);
  atomicAdd(&uA.n.bincnt[bi1], 1u);
  __syncthreads();
  if (wv == 0) {
    u32 c0 = uA.n.bincnt[lane * 4 + 0], c1 = uA.n.bincnt[lane * 4 + 1];
    u32 c2 = uA.n.bincnt[lane * 4 + 2], c3 = uA.n.bincnt[lane * 4 + 3];
    u32 ssum = c0 + c1 + c2 + c3;
    u32 inc = ssum;
    for (int d = 1; d < 64; d <<= 1) {
      u32 v = __shfl_up(inc, d);
      if (lane >= d) inc += v;
    }
    u32 excl = inc - ssum;
    uA.n.binstart[lane * 4 + 0] = excl;
    uA.n.binstart[lane * 4 + 1] = excl + c0;
    uA.n.binstart[lane * 4 + 2] = excl + c0 + c1;
    uA.n.binstart[lane * 4 + 3] = excl + c0 + c1 + c2;
    if (lane == 63) uA.n.binstart[NSB] = inc;
  }
  __syncthreads();
  {
    u32 s0 = uA.n.binstart[bi0] + atomicAdd(&uA.n.binfill[bi0], 1u);
    uA.n.cpos[s0] = (u16)t;
    u32 s1 = uA.n.binstart[bi1] + atomicAdd(&uA.n.binfill[bi1], 1u);
    uA.n.cpos[s1] = (u16)(t + 1024);
  }

  // ---- in-chunk 64x64 exact adjacency rows, kept in registers ----
  u64 m0 = 0ull, m1 = 0ull;
  {
    int c0 = wv * 64, c1 = (wv + 16) * 64;
    for (int j = 0; j < 64; ++j) {
      float2 bb0 = box[c0 + j];
      float2 bb1 = box[c1 + j];
      float w0 = __fsub_rn(bb0.y, bb0.x);
      float w1 = __fsub_rn(bb1.y, bb1.x);
      if ((j != lane) & iou_gt(bx0, wa0, bb0, w0)) m0 |= 1ull << j;
      if ((j != lane) & iou_gt(bx1, wa1, bb1, w1)) m1 |= 1ull << j;
    }
  }
  __syncthreads();   // cpos/binstart complete

  // ---- greedy NMS: scan chunk -> transposed marking of later candidates ----
  for (int ch = 0; ch < NCH; ++ch) {
    if (wv == (ch & 15)) {
      u32 supw = uA.n.supm[ch * 2 + (lane >> 5)];
      bool mysup = (supw >> (lane & 31)) & 1u;
      u64 s = __ballot(mysup);
      u64 rem = ~s;
      u64 kept = 0ull;
      u64 myrow = (ch < 16) ? m0 : m1;
      u32 mlo = (u32)myrow, mhi = (u32)(myrow >> 32);
      while (rem) {
        int i = __builtin_ctzll(rem);
        kept |= 1ull << i;
        u32 rlo = (u32)__builtin_amdgcn_readlane((int)mlo, i);
        u32 rhi = (u32)__builtin_amdgcn_readlane((int)mhi, i);
        u64 row = ((u64)rhi << 32) | (u64)rlo;
        rem &= ~(row | (1ull << i));
      }
      if ((kept >> lane) & 1ull) {
        float2 mb = (ch < 16) ? bx0 : bx1;
        // conservative center-window: IoU>0.5 => other's center in [x1,x2];
        // +-0.25 margin absorbs all f32 rounding and bin quantization.
        float loc_ = fmaxf(__fsub_rn(mb.x, 0.25f), 0.0f);
        float hic_ = __fadd_rn(mb.y, 0.25f);
        int blo = (int)(loc_ * sbin); if (blo > NSB - 1) blo = NSB - 1;
        int bhi = (int)(hic_ * sbin); if (bhi > NSB - 1) bhi = NSB - 1;
        u32 lo = uA.n.binstart[blo];
        u32 hi = uA.n.binstart[bhi + 1];
        u32 li = (u32)__popcll(kept & ((1ull << lane) - 1ull));
        uA.n.wbox[li] = mb;
        uA.n.wrange[li] = (lo << 16) | hi;
      }
      if (lane == 0) {
        keepw[ch * 2]     = (u32)kept;
        keepw[ch * 2 + 1] = (u32)(kept >> 32);
        uA.n.nkeptS = (u32)__popcll(kept);
        uA.n.LcntS += (u32)__popcll(kept);
      }
    }
    __syncthreads();   // (A) scan results visible
    u32 Ltot = uA.n.LcntS;
    if (Ltot >= POST_NMS) {
      // outputs fully determined by the first 512 kept: zero undecided chunks
      for (int w2 = ch * 2 + 2 + t; w2 < NCH * 2; w2 += NTHR) keepw[w2] = 0u;
      break;
    }
    u32 nk = uA.n.nkeptS;
    for (u32 k2 = (u32)wv; k2 < nk; k2 += 16) {
      float2 kb = uA.n.wbox[k2];
      u32 rng = uA.n.wrange[k2];
      u32 lo = rng >> 16, hi = rng & 0xFFFFu;
      float wbk = __fsub_rn(kb.y, kb.x);
      for (u32 idx = lo + (u32)lane; idx < hi; idx += 64) {
        u32 p = uA.n.cpos[idx];
        float2 bp = box[p];
        float wp = __fsub_rn(bp.y, bp.x);
        if (iou_gt(bp, wp, kb, wbk))
          atomicOr(&uA.n.supm[p >> 5], 1u << (p & 31));
      }
    }
    __syncthreads();   // (B) marking visible before next chunk's scan
  }
  __syncthreads();     // keepw zeroing (early-exit path) visible

  // ---- stable partition: kept first (ascending), then unkept (ascending) ----
  if (wv == 0) {
    u32 wvv = keepw[lane];
    u32 pc = __popc(wvv);
    u32 inc = pc;
    for (int d = 1; d < 64; d <<= 1) {
      u32 v = __shfl_up(inc, d);
      if (lane >= d) inc += v;
    }
    wpre[lane] = inc - pc;
    if (lane == 63) wpre[64] = inc;
  }
  __syncthreads();
  u32 K = wpre[64];
  size_t selOff = (size_t)BATCH * POST_NMS * 2;
  size_t valOff = selOff + (size_t)BATCH * POST_NMS;
#pragma unroll
  for (int r = 0; r < 2; ++r) {
    int p = t + NTHR * r;
    u32 w = p >> 5, bit = p & 31;
    u32 wvv = keepw[w];
    bool kp = (wvv >> bit) & 1u;
    u32 kpref = wpre[w] + __popc(wvv & ((1u << bit) - 1u));
    u32 rr = kp ? kpref : (K + ((u32)p - kpref));
    if (rr < POST_NMS) {
      float2 bxo = kp ? box[p] : make_float2(0.0f, 0.0f);
      size_t ob = (size_t)b * POST_NMS + rr;
      out[ob * 2 + 0] = bxo.x;
      out[ob * 2 + 1] = bxo.y;
      out[selOff + ob] = (float)p;
      out[valOff + ob] = kp ? 1.0f : 0.0f;
    }
  }
}

extern "C" void kernel_launch(void* const* d_in, const int* in_sizes, int n_in,
                              void* d_out, int out_size, void* d_ws, size_t ws_size,
                              hipStream_t stream) {
  const float* obj    = (const float*)d_in[0];
  const float* delta  = (const float*)d_in[1];
  const float* anchor = (const float*)d_in[2];
  const int*   imgp   = (const int*)d_in[3];
  float* out = (float*)d_out;

  unsigned char* w = (unsigned char*)d_ws;
  u32* hist = (u32*)(w);
  u32* cnt  = (u32*)(w + OFF_CNT);
  u32* cutb = (u32*)(w + OFF_CUT);
  u64* cand = (u64*)(w + OFF_CAND);

  hipMemsetAsync(w, 0, OFF_CUT, stream);   // re-init hist+cnt every call

  hist_kernel<<<dim3(512), dim3(256), 0, stream>>>(obj, hist);
  cut_kernel<<<dim3(BATCH), dim3(256), 0, stream>>>(hist, cutb);
  collect_kernel<<<dim3(512), dim3(256), 0, stream>>>(obj, cutb, cnt, cand);
  finalize_kernel<<<dim3(BATCH), dim3(NTHR), 0, stream>>>(delta, anchor, imgp, cnt, cand, out);
}